// Round 13
// baseline (149.898 us; speedup 1.0000x reference)
//
#include <hip/hip_runtime.h>
#include <math.h>

typedef __attribute__((ext_vector_type(8))) short short8;
typedef __attribute__((ext_vector_type(4))) float f32x4;

namespace {
constexpr int BATCH = 4096;
constexpr int SEQT  = 256;
constexpr int INSZ  = 24;
constexpr int H     = 40;
constexpr int NOUT  = 24;
constexpr int R     = 4;     // rows per block, grid = 1024 (4 independent blocks/CU)
constexpr int NT    = 256;   // 4 waves: 0-2 gate tiles, 3 = x-stage + FC(lagged)

__device__ __forceinline__ unsigned short f2bf(float f) {
  unsigned int u = __float_as_uint(f);
  return (unsigned short)((u + 0x7FFFu + ((u >> 16) & 1u)) >> 16);  // RNE
}
__device__ __forceinline__ unsigned short cvt_bf16(float f) {
  float r;
  asm("v_cvt_pk_bf16_f32 %0, %1, %2" : "=v"(r) : "v"(f), "v"(f));
  return (unsigned short)__float_as_uint(r);   // low 16 bits = bf16(f), RNE
}
__device__ __forceinline__ unsigned int cvt_pk2(float lo, float hi) {
  float r;
  asm("v_cvt_pk_bf16_f32 %0, %1, %2" : "=v"(r) : "v"(lo), "v"(hi));
  return __float_as_uint(r);   // {bf16(hi), bf16(lo)}
}
__device__ __forceinline__ float4 ld4(const float* p) {
  return *reinterpret_cast<const float4*>(p);
}
// Native-rate transcendentals (v_exp_f32/v_rcp_f32) — avoids IEEE div sequence.
__device__ __forceinline__ float sigm(float v) {
  return __builtin_amdgcn_rcpf(1.0f + __builtin_amdgcn_exp2f(v * -1.442695041f));
}
__device__ __forceinline__ float tanh_fast(float v) {
  return fmaf(2.0f,
              __builtin_amdgcn_rcpf(1.0f + __builtin_amdgcn_exp2f(v * -2.885390082f)),
              -1.0f);
}
}  // namespace

// Raw barrier: drain only LDS ops; global loads/stores stay in flight.
#define BAR()                                              \
  asm volatile("s_waitcnt lgkmcnt(0)" ::: "memory");       \
  __builtin_amdgcn_s_barrier();                            \
  __builtin_amdgcn_sched_barrier(0);

// Four independent 4-row blocks per CU (grid=1024): separate hardware barriers
// -> phase drift; each SIMD interleaves 4 de-correlated latency chains (R12
// proved the mechanism at 2 blocks: 135->122). Real rows at A-rows lq*4 =
// {0,4,8,12}: every lane's acc[0] is its one real row -> gate math 1 item/lane,
// per-CU VALU work identical to R10/R12. Pad A-rows stay zero forever.
__global__ __launch_bounds__(NT) void gru_mfma4(
    const float* __restrict__ x, const float* __restrict__ Wih,
    const float* __restrict__ Whh, const float* __restrict__ bih,
    const float* __restrict__ bhh, const float* __restrict__ Wfc,
    const float* __restrict__ bfc, float* __restrict__ out,
    float* __restrict__ hid) {
  __shared__ __align__(16) unsigned short Abuf[2 * 1024];

  const int tid = threadIdx.x;
  const int l   = tid & 63;
  const int w   = tid >> 6;
  const int lm  = l & 15;
  const int lq  = l >> 4;
  const int gb0 = blockIdx.x * R;

  reinterpret_cast<uint4*>(Abuf)[tid] = make_uint4(0, 0, 0, 0);  // zero both buffers

  const int aBase0 = ((lm * 64 + lq * 8)      ^ ((lm & 7) << 3));
  const int aBase1 = ((lm * 64 + lq * 8 + 32) ^ ((lm & 7) << 3));

  // ---------------- gate role (waves 0..2) ----------------
  short8 B[4][2];
  float bias[4] = {0, 0, 0, 0};
  float hold0 = 0.0f;
  int aw0 = 0;
  int u = 0;
  bool gvalid = false;
  if (w < 3) {
    u = w * 16 + lm;
    gvalid = (u < H);
#pragma unroll
    for (int z = 0; z < 4; ++z) {
#pragma unroll
      for (int kt = 0; kt < 2; ++kt) {
        short8 b;
#pragma unroll
        for (int j = 0; j < 8; ++j) {
          const int k = kt * 32 + lq * 8 + j;
          float v = 0.0f;
          if (gvalid) {
            if (z == 0)      v = (k < 24) ? Wih[u * 24 + k]          : Whh[u * 40 + (k - 24)];
            else if (z == 1) v = (k < 24) ? Wih[(40 + u) * 24 + k]   : Whh[(40 + u) * 40 + (k - 24)];
            else if (z == 2) v = (k < 24) ? Wih[(80 + u) * 24 + k]   : 0.0f;
            else             v = (k < 24) ? 0.0f                     : Whh[(80 + u) * 40 + (k - 24)];
          }
          b[j] = (short)f2bf(v);
        }
        B[z][kt] = b;
      }
    }
    if (gvalid) {
      bias[0] = bih[u] + bhh[u];
      bias[1] = bih[40 + u] + bhh[40 + u];
      bias[2] = bih[80 + u];           // n input bias
      bias[3] = bhh[80 + u];           // n hidden bias (scaled by r)
    }
    {
      const int arow = lq * 4;         // real row of this lane (acc index 0)
      aw0 = ((arow * 64 + 24 + u) ^ ((arow & 7) << 3));
    }
  }

  // ---------------- x-stage + FC role (wave 3) ----------------
  short8 F[2][2];
  float biasF[2] = {0, 0};
  float* orow0 = nullptr;
  const float* xp0 = nullptr;
  int xw0 = 0;
  bool xv = false;
  float4 xA0 = make_float4(0, 0, 0, 0), xB0 = make_float4(0, 0, 0, 0);
  if (w == 3) {
#pragma unroll
    for (int f = 0; f < 2; ++f) {
      const int o = f * 16 + lm;
#pragma unroll
      for (int kt = 0; kt < 2; ++kt) {
        short8 b;
#pragma unroll
        for (int j = 0; j < 8; ++j) {
          const int k = kt * 32 + lq * 8 + j;
          const float v = (o < NOUT && k >= 24) ? Wfc[o * H + (k - 24)] : 0.0f;
          b[j] = (short)f2bf(v);
        }
        F[f][kt] = b;
      }
      biasF[f] = (o < NOUT) ? bfc[o] : 0.0f;
    }
    orow0 = out + ((size_t)(gb0 + lq) * SEQT) * NOUT;

    // x staging: 24 float4 chunks (4 rows x 6), lanes l<24; row r -> A-row 4r
    xv = (l < 24);
    const int xr = l / 6, xc = (l - xr * 6) * 4;
    const int ar_ = xr << 2;
    if (xv) xp0 = x + ((size_t)(gb0 + xr) * SEQT) * INSZ + xc;
    xw0 = ((ar_ * 64 + xc) ^ ((ar_ & 7) << 3));
  }

  __syncthreads();  // zero-init visible

  if (w == 3 && xv) {  // stage x(0) into buf0; prefetch x(1)->xA, x(2)->xB
    const float4 v0 = ld4(xp0);
    *reinterpret_cast<uint2*>(&Abuf[xw0]) =
        make_uint2(cvt_pk2(v0.x, v0.y), cvt_pk2(v0.z, v0.w));
    xA0 = ld4(xp0 + 1 * INSZ);
    xB0 = ld4(xp0 + 2 * INSZ);
  }
  __syncthreads();  // x(0) staged

// 7-MFMA gate step (nx kt=1 tile identically zero -> skipped); gate math on
// the single real acc row.
#define GATE_STEP(BO, NBO)                                                      \
  if (w < 3) {                                                                  \
    const short8 A0 = *reinterpret_cast<const short8*>(&Abuf[(BO) + aBase0]);   \
    const short8 A1 = *reinterpret_cast<const short8*>(&Abuf[(BO) + aBase1]);   \
    f32x4 ar = {bias[0], bias[0], bias[0], bias[0]};                            \
    f32x4 az = {bias[1], bias[1], bias[1], bias[1]};                            \
    f32x4 ax = {bias[2], bias[2], bias[2], bias[2]};                            \
    f32x4 ah = {bias[3], bias[3], bias[3], bias[3]};                            \
    ar = __builtin_amdgcn_mfma_f32_16x16x32_bf16(A0, B[0][0], ar, 0, 0, 0);     \
    az = __builtin_amdgcn_mfma_f32_16x16x32_bf16(A0, B[1][0], az, 0, 0, 0);     \
    ax = __builtin_amdgcn_mfma_f32_16x16x32_bf16(A0, B[2][0], ax, 0, 0, 0);     \
    ah = __builtin_amdgcn_mfma_f32_16x16x32_bf16(A0, B[3][0], ah, 0, 0, 0);     \
    ar = __builtin_amdgcn_mfma_f32_16x16x32_bf16(A1, B[0][1], ar, 0, 0, 0);     \
    az = __builtin_amdgcn_mfma_f32_16x16x32_bf16(A1, B[1][1], az, 0, 0, 0);     \
    ah = __builtin_amdgcn_mfma_f32_16x16x32_bf16(A1, B[3][1], ah, 0, 0, 0);     \
    {                                                                           \
      const float rr = sigm(ar[0]);                                             \
      const float zz = sigm(az[0]);                                             \
      const float nn = tanh_fast(fmaf(rr, ah[0], ax[0]));                       \
      const float h  = fmaf(zz, hold0 - nn, nn);                                \
      hold0 = h;                                                                \
      if (gvalid) Abuf[(NBO) + aw0] = cvt_bf16(h);                              \
    }                                                                           \
  }

// stage x(T) into buffer TBO from reg XS; reload XS <- x(T+2)
#define XSTAGE(T, TBO, XS)                                                      \
  if (xv) {                                                                     \
    if ((T) < SEQT) {                                                           \
      *reinterpret_cast<uint2*>(&Abuf[(TBO) + xw0]) =                           \
          make_uint2(cvt_pk2(XS.x, XS.y), cvt_pk2(XS.z, XS.w));                 \
    }                                                                           \
    if ((T) + 2 < SEQT) XS = ld4(xp0 + (size_t)((T) + 2) * INSZ);               \
  }

// FC for step T, reading buffer BO (= buffer holding h(T)); 1 real row/lane
#define FC_STEP(T, BO)                                                          \
  {                                                                             \
    const short8 hA0 = *reinterpret_cast<const short8*>(&Abuf[(BO) + aBase0]);  \
    const short8 hA1 = *reinterpret_cast<const short8*>(&Abuf[(BO) + aBase1]);  \
    f32x4 f0 = {biasF[0], biasF[0], biasF[0], biasF[0]};                        \
    f32x4 f1 = {biasF[1], biasF[1], biasF[1], biasF[1]};                        \
    f0 = __builtin_amdgcn_mfma_f32_16x16x32_bf16(hA0, F[0][0], f0, 0, 0, 0);    \
    f1 = __builtin_amdgcn_mfma_f32_16x16x32_bf16(hA0, F[1][0], f1, 0, 0, 0);    \
    f0 = __builtin_amdgcn_mfma_f32_16x16x32_bf16(hA1, F[0][1], f0, 0, 0, 0);    \
    f1 = __builtin_amdgcn_mfma_f32_16x16x32_bf16(hA1, F[1][1], f1, 0, 0, 0);    \
    orow0[(size_t)(T) * NOUT + lm] = sigm(f0[0]);                               \
    if (lm < 8) orow0[(size_t)(T) * NOUT + 16 + lm] = sigm(f1[0]);              \
  }

  for (int tt = 0; tt < SEQT; tt += 2) {
    // ---- interval tt: bo=0, nbo=1024 ----
    GATE_STEP(0, 1024)
    if (w == 3) {
      XSTAGE(tt + 1, 1024, xA0)
      if (tt > 0) FC_STEP(tt - 1, 0)
    }
    BAR()
    // ---- interval tt+1: bo=1024, nbo=0 ----
    GATE_STEP(1024, 0)
    if (w == 3) {
      XSTAGE(tt + 2, 0, xB0)
      FC_STEP(tt, 1024)
    }
    BAR()
  }
  // epilogue: FC for the final step (h(255) lives in buf0)
  if (w == 3) FC_STEP(SEQT - 1, 0)

  // final hidden state from registers (1 real row per lane)
  if (w < 3 && gvalid)
    hid[(size_t)(gb0 + lq) * H + u] = hold0;
}

extern "C" void kernel_launch(void* const* d_in, const int* in_sizes, int n_in,
                              void* d_out, int out_size, void* d_ws, size_t ws_size,
                              hipStream_t stream) {
  const float* x   = (const float*)d_in[0];
  const float* Wih = (const float*)d_in[1];
  const float* Whh = (const float*)d_in[2];
  const float* bih = (const float*)d_in[3];
  const float* bhh = (const float*)d_in[4];
  const float* Wfc = (const float*)d_in[5];
  const float* bfc = (const float*)d_in[6];
  float* out = (float*)d_out;
  float* hid = out + (size_t)BATCH * SEQT * NOUT;

  dim3 grid(BATCH / R);
  dim3 block(NT);
  hipLaunchKernelGGL(gru_mfma4, grid, block, 0, stream,
                     x, Wih, Whh, bih, bhh, Wfc, bfc, out, hid);
}

// Round 14
// 131.569 us; speedup vs baseline: 1.1393x; 1.1393x over previous
//
#include <hip/hip_runtime.h>
#include <math.h>

typedef __attribute__((ext_vector_type(8))) short short8;
typedef __attribute__((ext_vector_type(4))) float f32x4;

namespace {
constexpr int BATCH = 4096;
constexpr int SEQT  = 256;
constexpr int INSZ  = 24;
constexpr int H     = 40;
constexpr int NOUT  = 24;
constexpr int R     = 8;     // rows per block, grid = 512 (2 independent blocks/CU)
constexpr int NT    = 256;   // 4 waves: 0-2 gate tiles, 3 = x-stage + FC(lagged)

__device__ __forceinline__ unsigned short f2bf(float f) {
  unsigned int u = __float_as_uint(f);
  return (unsigned short)((u + 0x7FFFu + ((u >> 16) & 1u)) >> 16);  // RNE
}
__device__ __forceinline__ unsigned short cvt_bf16(float f) {
  float r;
  asm("v_cvt_pk_bf16_f32 %0, %1, %2" : "=v"(r) : "v"(f), "v"(f));
  return (unsigned short)__float_as_uint(r);   // low 16 bits = bf16(f), RNE
}
__device__ __forceinline__ unsigned int cvt_pk2(float lo, float hi) {
  float r;
  asm("v_cvt_pk_bf16_f32 %0, %1, %2" : "=v"(r) : "v"(lo), "v"(hi));
  return __float_as_uint(r);   // {bf16(hi), bf16(lo)}
}
__device__ __forceinline__ float4 ld4(const float* p) {
  return *reinterpret_cast<const float4*>(p);
}
// Native-rate transcendentals (v_exp_f32/v_rcp_f32) — avoids IEEE div sequence.
__device__ __forceinline__ float sigm(float v) {
  return __builtin_amdgcn_rcpf(1.0f + __builtin_amdgcn_exp2f(v * -1.442695041f));
}
__device__ __forceinline__ float tanh_fast(float v) {
  return fmaf(2.0f,
              __builtin_amdgcn_rcpf(1.0f + __builtin_amdgcn_exp2f(v * -2.885390082f)),
              -1.0f);
}
}  // namespace

// Raw barrier: drain only LDS ops; global loads/stores stay in flight.
#define BAR()                                              \
  asm volatile("s_waitcnt lgkmcnt(0)" ::: "memory");       \
  __builtin_amdgcn_s_barrier();                            \
  __builtin_amdgcn_sched_barrier(0);

// Two independent 8-row blocks per CU (grid=512, R12 structure — the measured
// sweet spot: 1 block=lockstep-bound, 4 blocks=DS-pipe/duplication-bound).
// Real rows at A-rows lq*4+{0,1}; pad rows stay zero. R14 adds: K-split MFMA
// accumulators (breaks the serial 2-MFMA chain), setprio(1) around the gate
// critical section (2 drifted blocks -> scheduler has role diversity), and
// depth-4 x prefetch (load-to-use ~4 intervals >> 900cy HBM miss).
__global__ __launch_bounds__(NT) void gru_mfma4(
    const float* __restrict__ x, const float* __restrict__ Wih,
    const float* __restrict__ Whh, const float* __restrict__ bih,
    const float* __restrict__ bhh, const float* __restrict__ Wfc,
    const float* __restrict__ bfc, float* __restrict__ out,
    float* __restrict__ hid) {
  __shared__ __align__(16) unsigned short Abuf[2 * 1024];

  const int tid = threadIdx.x;
  const int l   = tid & 63;
  const int w   = tid >> 6;
  const int lm  = l & 15;
  const int lq  = l >> 4;
  const int gb0 = blockIdx.x * R;

  reinterpret_cast<uint4*>(Abuf)[tid] = make_uint4(0, 0, 0, 0);  // zero both buffers

  const int aBase0 = ((lm * 64 + lq * 8)      ^ ((lm & 7) << 3));
  const int aBase1 = ((lm * 64 + lq * 8 + 32) ^ ((lm & 7) << 3));

  // ---------------- gate role (waves 0..2) ----------------
  short8 B[4][2];
  float bias[4] = {0, 0, 0, 0};
  float hold[2] = {0, 0};
  int aw[2] = {0, 0};
  int u = 0;
  bool gvalid = false;
  if (w < 3) {
    u = w * 16 + lm;
    gvalid = (u < H);
#pragma unroll
    for (int z = 0; z < 4; ++z) {
#pragma unroll
      for (int kt = 0; kt < 2; ++kt) {
        short8 b;
#pragma unroll
        for (int j = 0; j < 8; ++j) {
          const int k = kt * 32 + lq * 8 + j;
          float v = 0.0f;
          if (gvalid) {
            if (z == 0)      v = (k < 24) ? Wih[u * 24 + k]          : Whh[u * 40 + (k - 24)];
            else if (z == 1) v = (k < 24) ? Wih[(40 + u) * 24 + k]   : Whh[(40 + u) * 40 + (k - 24)];
            else if (z == 2) v = (k < 24) ? Wih[(80 + u) * 24 + k]   : 0.0f;
            else             v = (k < 24) ? 0.0f                     : Whh[(80 + u) * 40 + (k - 24)];
          }
          b[j] = (short)f2bf(v);
        }
        B[z][kt] = b;
      }
    }
    if (gvalid) {
      bias[0] = bih[u] + bhh[u];
      bias[1] = bih[40 + u] + bhh[40 + u];
      bias[2] = bih[80 + u];           // n input bias
      bias[3] = bhh[80 + u];           // n hidden bias (scaled by r)
    }
#pragma unroll
    for (int i = 0; i < 2; ++i) {
      const int arow = lq * 4 + i;     // real rows live at acc rows {0,1}
      aw[i] = ((arow * 64 + 24 + u) ^ ((arow & 7) << 3));
    }
  }

  // ---------------- x-stage + FC role (wave 3) ----------------
  short8 F[2][2];
  float biasF[2] = {0, 0};
  float* orow[2] = {nullptr, nullptr};
  const float* xp0 = nullptr;
  int xw0 = 0;
  bool xv = false;
  // depth-4 x prefetch: xQ[j] holds x(T) with T === j (mod 4)
  float4 xQ1 = make_float4(0,0,0,0), xQ2 = make_float4(0,0,0,0);
  float4 xQ3 = make_float4(0,0,0,0), xQ0 = make_float4(0,0,0,0);
  if (w == 3) {
#pragma unroll
    for (int f = 0; f < 2; ++f) {
      const int o = f * 16 + lm;
#pragma unroll
      for (int kt = 0; kt < 2; ++kt) {
        short8 b;
#pragma unroll
        for (int j = 0; j < 8; ++j) {
          const int k = kt * 32 + lq * 8 + j;
          const float v = (o < NOUT && k >= 24) ? Wfc[o * H + (k - 24)] : 0.0f;
          b[j] = (short)f2bf(v);
        }
        F[f][kt] = b;
      }
      biasF[f] = (o < NOUT) ? bfc[o] : 0.0f;
    }
#pragma unroll
    for (int i = 0; i < 2; ++i)
      orow[i] = out + ((size_t)(gb0 + lq * 2 + i) * SEQT) * NOUT;

    // x staging: 48 float4 chunks (8 rows x 6), lanes l<48; row r -> A-row
    // ar = (r>>1)*4 + (r&1)
    xv = (l < 48);
    const int xr = l / 6, xc = (l - xr * 6) * 4;
    const int ar_ = ((xr >> 1) << 2) + (xr & 1);
    if (xv) xp0 = x + ((size_t)(gb0 + xr) * SEQT) * INSZ + xc;
    xw0 = ((ar_ * 64 + xc) ^ ((ar_ & 7) << 3));
  }

  __syncthreads();  // zero-init visible

  if (w == 3 && xv) {  // stage x(0) into buf0; prefetch x(1..4)
    const float4 v0 = ld4(xp0);
    *reinterpret_cast<uint2*>(&Abuf[xw0]) =
        make_uint2(cvt_pk2(v0.x, v0.y), cvt_pk2(v0.z, v0.w));
    xQ1 = ld4(xp0 + 1 * INSZ);
    xQ2 = ld4(xp0 + 2 * INSZ);
    xQ3 = ld4(xp0 + 3 * INSZ);
    xQ0 = ld4(xp0 + 4 * INSZ);
  }
  __syncthreads();  // x(0) staged

// 7-MFMA gate step with K-split accumulators: for r/z/nh the two K-tiles go to
// INDEPENDENT accs (no MFMA->MFMA serial dep), summed on the 2 real elements
// with plain adds. nx has only the kt=0 tile (kt=1 identically zero).
// setprio(1) across the recurrence-critical section.
#define GATE_STEP(BO, NBO)                                                      \
  if (w < 3) {                                                                  \
    __builtin_amdgcn_s_setprio(1);                                              \
    const short8 A0 = *reinterpret_cast<const short8*>(&Abuf[(BO) + aBase0]);   \
    const short8 A1 = *reinterpret_cast<const short8*>(&Abuf[(BO) + aBase1]);   \
    const f32x4 zed = {0.0f, 0.0f, 0.0f, 0.0f};                                 \
    f32x4 ar0 = {bias[0], bias[0], bias[0], bias[0]};                           \
    f32x4 az0 = {bias[1], bias[1], bias[1], bias[1]};                           \
    f32x4 ax0 = {bias[2], bias[2], bias[2], bias[2]};                           \
    f32x4 ah0 = {bias[3], bias[3], bias[3], bias[3]};                           \
    ar0 = __builtin_amdgcn_mfma_f32_16x16x32_bf16(A0, B[0][0], ar0, 0, 0, 0);   \
    az0 = __builtin_amdgcn_mfma_f32_16x16x32_bf16(A0, B[1][0], az0, 0, 0, 0);   \
    ax0 = __builtin_amdgcn_mfma_f32_16x16x32_bf16(A0, B[2][0], ax0, 0, 0, 0);   \
    ah0 = __builtin_amdgcn_mfma_f32_16x16x32_bf16(A0, B[3][0], ah0, 0, 0, 0);   \
    f32x4 ar1 = __builtin_amdgcn_mfma_f32_16x16x32_bf16(A1, B[0][1], zed, 0, 0, 0); \
    f32x4 az1 = __builtin_amdgcn_mfma_f32_16x16x32_bf16(A1, B[1][1], zed, 0, 0, 0); \
    f32x4 ah1 = __builtin_amdgcn_mfma_f32_16x16x32_bf16(A1, B[3][1], zed, 0, 0, 0); \
    _Pragma("unroll")                                                           \
    for (int i = 0; i < 2; ++i) {                                               \
      const float rr = sigm(ar0[i] + ar1[i]);                                   \
      const float zz = sigm(az0[i] + az1[i]);                                   \
      const float nn = tanh_fast(fmaf(rr, ah0[i] + ah1[i], ax0[i]));            \
      const float h  = fmaf(zz, hold[i] - nn, nn);                              \
      hold[i] = h;                                                              \
      if (gvalid) Abuf[(NBO) + aw[i]] = cvt_bf16(h);                            \
    }                                                                           \
    __builtin_amdgcn_s_setprio(0);                                              \
  }

// stage x(T) into buffer TBO from reg XS; reload XS <- x(T+4)
#define XSTAGE(T, TBO, XS)                                                      \
  if (xv) {                                                                     \
    if ((T) < SEQT) {                                                           \
      *reinterpret_cast<uint2*>(&Abuf[(TBO) + xw0]) =                           \
          make_uint2(cvt_pk2(XS.x, XS.y), cvt_pk2(XS.z, XS.w));                 \
    }                                                                           \
    if ((T) + 4 < SEQT) XS = ld4(xp0 + (size_t)((T) + 4) * INSZ);               \
  }

// FC for step T, reading buffer BO (= buffer holding h(T)); 2 real rows/lane
#define FC_STEP(T, BO)                                                          \
  {                                                                             \
    const short8 hA0 = *reinterpret_cast<const short8*>(&Abuf[(BO) + aBase0]);  \
    const short8 hA1 = *reinterpret_cast<const short8*>(&Abuf[(BO) + aBase1]);  \
    f32x4 f0 = {biasF[0], biasF[0], biasF[0], biasF[0]};                        \
    f32x4 f1 = {biasF[1], biasF[1], biasF[1], biasF[1]};                        \
    f0 = __builtin_amdgcn_mfma_f32_16x16x32_bf16(hA0, F[0][0], f0, 0, 0, 0);    \
    f1 = __builtin_amdgcn_mfma_f32_16x16x32_bf16(hA0, F[1][0], f1, 0, 0, 0);    \
    f0 = __builtin_amdgcn_mfma_f32_16x16x32_bf16(hA1, F[0][1], f0, 0, 0, 0);    \
    f1 = __builtin_amdgcn_mfma_f32_16x16x32_bf16(hA1, F[1][1], f1, 0, 0, 0);    \
    _Pragma("unroll")                                                           \
    for (int i = 0; i < 2; ++i) {                                               \
      orow[i][(size_t)(T) * NOUT + lm] = sigm(f0[i]);                           \
      if (lm < 8) orow[i][(size_t)(T) * NOUT + 16 + lm] = sigm(f1[i]);          \
    }                                                                           \
  }

  for (int tt = 0; tt < SEQT; tt += 4) {
    // ---- interval tt: bo=0, nbo=1024 ----
    GATE_STEP(0, 1024)
    if (w == 3) {
      XSTAGE(tt + 1, 1024, xQ1)
      if (tt > 0) FC_STEP(tt - 1, 0)
    }
    BAR()
    // ---- interval tt+1: bo=1024, nbo=0 ----
    GATE_STEP(1024, 0)
    if (w == 3) {
      XSTAGE(tt + 2, 0, xQ2)
      FC_STEP(tt, 1024)
    }
    BAR()
    // ---- interval tt+2: bo=0, nbo=1024 ----
    GATE_STEP(0, 1024)
    if (w == 3) {
      XSTAGE(tt + 3, 1024, xQ3)
      FC_STEP(tt + 1, 0)
    }
    BAR()
    // ---- interval tt+3: bo=1024, nbo=0 ----
    GATE_STEP(1024, 0)
    if (w == 3) {
      XSTAGE(tt + 4, 0, xQ0)
      FC_STEP(tt + 2, 1024)
    }
    BAR()
  }
  // epilogue: FC for the final step (h(255) lives in buf0)
  if (w == 3) FC_STEP(SEQT - 1, 0)

  // final hidden state from registers (2 real rows per lane)
  if (w < 3 && gvalid) {
#pragma unroll
    for (int i = 0; i < 2; ++i)
      hid[(size_t)(gb0 + lq * 2 + i) * H + u] = hold[i];
  }
}

extern "C" void kernel_launch(void* const* d_in, const int* in_sizes, int n_in,
                              void* d_out, int out_size, void* d_ws, size_t ws_size,
                              hipStream_t stream) {
  const float* x   = (const float*)d_in[0];
  const float* Wih = (const float*)d_in[1];
  const float* Whh = (const float*)d_in[2];
  const float* bih = (const float*)d_in[3];
  const float* bhh = (const float*)d_in[4];
  const float* Wfc = (const float*)d_in[5];
  const float* bfc = (const float*)d_in[6];
  float* out = (float*)d_out;
  float* hid = out + (size_t)BATCH * SEQT * NOUT;

  dim3 grid(BATCH / R);
  dim3 block(NT);
  hipLaunchKernelGGL(gru_mfma4, grid, block, 0, stream,
                     x, Wih, Whh, bih, bhh, Wfc, bfc, out, hid);
}

// Round 15
// 112.670 us; speedup vs baseline: 1.3304x; 1.1677x over previous
//
#include <hip/hip_runtime.h>
#include <math.h>

typedef __attribute__((ext_vector_type(8))) short short8;
typedef __attribute__((ext_vector_type(4))) float f32x4;

namespace {
constexpr int BATCH = 4096;
constexpr int SEQT  = 256;
constexpr int INSZ  = 24;
constexpr int H     = 40;
constexpr int NOUT  = 24;
constexpr int R     = 8;     // rows per block, grid = 512 (2 independent blocks/CU)
constexpr int NT    = 256;   // 4 waves: 0-2 gate tiles, 3 = x-stage + FC(lagged)

__device__ __forceinline__ unsigned short f2bf(float f) {
  unsigned int u = __float_as_uint(f);
  return (unsigned short)((u + 0x7FFFu + ((u >> 16) & 1u)) >> 16);  // RNE
}
__device__ __forceinline__ unsigned short cvt_bf16(float f) {
  float r;
  asm("v_cvt_pk_bf16_f32 %0, %1, %2" : "=v"(r) : "v"(f), "v"(f));
  return (unsigned short)__float_as_uint(r);   // low 16 bits = bf16(f), RNE
}
__device__ __forceinline__ unsigned int cvt_pk2(float lo, float hi) {
  float r;
  asm("v_cvt_pk_bf16_f32 %0, %1, %2" : "=v"(r) : "v"(lo), "v"(hi));
  return __float_as_uint(r);   // {bf16(hi), bf16(lo)}
}
__device__ __forceinline__ float4 ld4(const float* p) {
  return *reinterpret_cast<const float4*>(p);
}
// Native-rate transcendentals (v_exp_f32/v_rcp_f32) — avoids IEEE div sequence.
__device__ __forceinline__ float sigm(float v) {
  return __builtin_amdgcn_rcpf(1.0f + __builtin_amdgcn_exp2f(v * -1.442695041f));
}
__device__ __forceinline__ float tanh_fast(float v) {
  return fmaf(2.0f,
              __builtin_amdgcn_rcpf(1.0f + __builtin_amdgcn_exp2f(v * -2.885390082f)),
              -1.0f);
}
}  // namespace

// Raw barrier: drain only LDS ops; global loads/stores stay in flight.
#define BAR()                                              \
  asm volatile("s_waitcnt lgkmcnt(0)" ::: "memory");       \
  __builtin_amdgcn_s_barrier();                            \
  __builtin_amdgcn_sched_barrier(0);

// R12 structure (measured sweet spot: 2 independent 8-row blocks/CU; 1 block =
// lockstep-bound, 4 = DS-pipe-bound). Real rows at A-rows lq*4+{0,1}; pad rows
// zero forever. R15 trims vs R12: (a) persistent-zero MFMA C-in — accumulators
// are never re-initialized per step (saves ~16 mov/accvgpr_write per gate wave
// per step); biases added in the scalar epilogue on the 2 real elements only;
// (b) depth-4 x prefetch (load-to-use ~4 intervals >> 900cy HBM miss).
// No setprio / no K-split (the R14 bundle regressed).
__global__ __launch_bounds__(NT) void gru_mfma4(
    const float* __restrict__ x, const float* __restrict__ Wih,
    const float* __restrict__ Whh, const float* __restrict__ bih,
    const float* __restrict__ bhh, const float* __restrict__ Wfc,
    const float* __restrict__ bfc, float* __restrict__ out,
    float* __restrict__ hid) {
  __shared__ __align__(16) unsigned short Abuf[2 * 1024];

  const int tid = threadIdx.x;
  const int l   = tid & 63;
  const int w   = tid >> 6;
  const int lm  = l & 15;
  const int lq  = l >> 4;
  const int gb0 = blockIdx.x * R;

  reinterpret_cast<uint4*>(Abuf)[tid] = make_uint4(0, 0, 0, 0);  // zero both buffers

  const int aBase0 = ((lm * 64 + lq * 8)      ^ ((lm & 7) << 3));
  const int aBase1 = ((lm * 64 + lq * 8 + 32) ^ ((lm & 7) << 3));

  // ---------------- gate role (waves 0..2) ----------------
  short8 B[4][2];
  float bias[4] = {0, 0, 0, 0};
  float hold[2] = {0, 0};
  int aw[2] = {0, 0};
  int u = 0;
  bool gvalid = false;
  if (w < 3) {
    u = w * 16 + lm;
    gvalid = (u < H);
#pragma unroll
    for (int z = 0; z < 4; ++z) {
#pragma unroll
      for (int kt = 0; kt < 2; ++kt) {
        short8 b;
#pragma unroll
        for (int j = 0; j < 8; ++j) {
          const int k = kt * 32 + lq * 8 + j;
          float v = 0.0f;
          if (gvalid) {
            if (z == 0)      v = (k < 24) ? Wih[u * 24 + k]          : Whh[u * 40 + (k - 24)];
            else if (z == 1) v = (k < 24) ? Wih[(40 + u) * 24 + k]   : Whh[(40 + u) * 40 + (k - 24)];
            else if (z == 2) v = (k < 24) ? Wih[(80 + u) * 24 + k]   : 0.0f;
            else             v = (k < 24) ? 0.0f                     : Whh[(80 + u) * 40 + (k - 24)];
          }
          b[j] = (short)f2bf(v);
        }
        B[z][kt] = b;
      }
    }
    if (gvalid) {
      bias[0] = bih[u] + bhh[u];
      bias[1] = bih[40 + u] + bhh[40 + u];
      bias[2] = bih[80 + u];           // n input bias
      bias[3] = bhh[80 + u];           // n hidden bias (scaled by r)
    }
#pragma unroll
    for (int i = 0; i < 2; ++i) {
      const int arow = lq * 4 + i;     // real rows live at acc rows {0,1}
      aw[i] = ((arow * 64 + 24 + u) ^ ((arow & 7) << 3));
    }
  }

  // ---------------- x-stage + FC role (wave 3) ----------------
  short8 F[2][2];
  float biasF[2] = {0, 0};
  float* orow[2] = {nullptr, nullptr};
  const float* xp0 = nullptr;
  int xw0 = 0;
  bool xv = false;
  // depth-4 x prefetch: xQj holds x(T) with T === j (mod 4)
  float4 xQ1 = make_float4(0,0,0,0), xQ2 = make_float4(0,0,0,0);
  float4 xQ3 = make_float4(0,0,0,0), xQ0 = make_float4(0,0,0,0);
  if (w == 3) {
#pragma unroll
    for (int f = 0; f < 2; ++f) {
      const int o = f * 16 + lm;
#pragma unroll
      for (int kt = 0; kt < 2; ++kt) {
        short8 b;
#pragma unroll
        for (int j = 0; j < 8; ++j) {
          const int k = kt * 32 + lq * 8 + j;
          const float v = (o < NOUT && k >= 24) ? Wfc[o * H + (k - 24)] : 0.0f;
          b[j] = (short)f2bf(v);
        }
        F[f][kt] = b;
      }
      biasF[f] = (o < NOUT) ? bfc[o] : 0.0f;
    }
#pragma unroll
    for (int i = 0; i < 2; ++i)
      orow[i] = out + ((size_t)(gb0 + lq * 2 + i) * SEQT) * NOUT;

    // x staging: 48 float4 chunks (8 rows x 6), lanes l<48; row r -> A-row
    // ar = (r>>1)*4 + (r&1)
    xv = (l < 48);
    const int xr = l / 6, xc = (l - xr * 6) * 4;
    const int ar_ = ((xr >> 1) << 2) + (xr & 1);
    if (xv) xp0 = x + ((size_t)(gb0 + xr) * SEQT) * INSZ + xc;
    xw0 = ((ar_ * 64 + xc) ^ ((ar_ & 7) << 3));
  }

  // persistent zero C for all MFMAs — never written, no per-step acc init
  const f32x4 kZero = {0.0f, 0.0f, 0.0f, 0.0f};

  __syncthreads();  // zero-init visible

  if (w == 3 && xv) {  // stage x(0) into buf0; prefetch x(1..4)
    const float4 v0 = ld4(xp0);
    *reinterpret_cast<uint2*>(&Abuf[xw0]) =
        make_uint2(cvt_pk2(v0.x, v0.y), cvt_pk2(v0.z, v0.w));
    xQ1 = ld4(xp0 + 1 * INSZ);
    xQ2 = ld4(xp0 + 2 * INSZ);
    xQ3 = ld4(xp0 + 3 * INSZ);
    xQ0 = ld4(xp0 + 4 * INSZ);
  }
  __syncthreads();  // x(0) staged

// 7-MFMA gate step, zero-C chained (acc regs never re-initialized); biases
// added on the 2 real elements in the epilogue. nx kt=1 tile identically zero.
#define GATE_STEP(BO, NBO)                                                      \
  if (w < 3) {                                                                  \
    const short8 A0 = *reinterpret_cast<const short8*>(&Abuf[(BO) + aBase0]);   \
    const short8 A1 = *reinterpret_cast<const short8*>(&Abuf[(BO) + aBase1]);   \
    f32x4 ar = __builtin_amdgcn_mfma_f32_16x16x32_bf16(A0, B[0][0], kZero, 0, 0, 0); \
    f32x4 az = __builtin_amdgcn_mfma_f32_16x16x32_bf16(A0, B[1][0], kZero, 0, 0, 0); \
    f32x4 ax = __builtin_amdgcn_mfma_f32_16x16x32_bf16(A0, B[2][0], kZero, 0, 0, 0); \
    f32x4 ah = __builtin_amdgcn_mfma_f32_16x16x32_bf16(A0, B[3][0], kZero, 0, 0, 0); \
    ar = __builtin_amdgcn_mfma_f32_16x16x32_bf16(A1, B[0][1], ar, 0, 0, 0);     \
    az = __builtin_amdgcn_mfma_f32_16x16x32_bf16(A1, B[1][1], az, 0, 0, 0);     \
    ah = __builtin_amdgcn_mfma_f32_16x16x32_bf16(A1, B[3][1], ah, 0, 0, 0);     \
    _Pragma("unroll")                                                           \
    for (int i = 0; i < 2; ++i) {                                               \
      const float rr = sigm(ar[i] + bias[0]);                                   \
      const float zz = sigm(az[i] + bias[1]);                                   \
      const float nn = tanh_fast(fmaf(rr, ah[i] + bias[3], ax[i] + bias[2]));   \
      const float h  = fmaf(zz, hold[i] - nn, nn);                              \
      hold[i] = h;                                                              \
      if (gvalid) Abuf[(NBO) + aw[i]] = cvt_bf16(h);                            \
    }                                                                           \
  }

// stage x(T) into buffer TBO from reg XS; reload XS <- x(T+4)
#define XSTAGE(T, TBO, XS)                                                      \
  if (xv) {                                                                     \
    if ((T) < SEQT) {                                                           \
      *reinterpret_cast<uint2*>(&Abuf[(TBO) + xw0]) =                           \
          make_uint2(cvt_pk2(XS.x, XS.y), cvt_pk2(XS.z, XS.w));                 \
    }                                                                           \
    if ((T) + 4 < SEQT) XS = ld4(xp0 + (size_t)((T) + 4) * INSZ);               \
  }

// FC for step T, reading buffer BO (= buffer holding h(T)); zero-C chained,
// bias added in epilogue; 2 real rows/lane
#define FC_STEP(T, BO)                                                          \
  {                                                                             \
    const short8 hA0 = *reinterpret_cast<const short8*>(&Abuf[(BO) + aBase0]);  \
    const short8 hA1 = *reinterpret_cast<const short8*>(&Abuf[(BO) + aBase1]);  \
    f32x4 f0 = __builtin_amdgcn_mfma_f32_16x16x32_bf16(hA0, F[0][0], kZero, 0, 0, 0); \
    f32x4 f1 = __builtin_amdgcn_mfma_f32_16x16x32_bf16(hA0, F[1][0], kZero, 0, 0, 0); \
    f0 = __builtin_amdgcn_mfma_f32_16x16x32_bf16(hA1, F[0][1], f0, 0, 0, 0);    \
    f1 = __builtin_amdgcn_mfma_f32_16x16x32_bf16(hA1, F[1][1], f1, 0, 0, 0);    \
    _Pragma("unroll")                                                           \
    for (int i = 0; i < 2; ++i) {                                               \
      orow[i][(size_t)(T) * NOUT + lm] = sigm(f0[i] + biasF[0]);                \
      if (lm < 8) orow[i][(size_t)(T) * NOUT + 16 + lm] = sigm(f1[i] + biasF[1]); \
    }                                                                           \
  }

  for (int tt = 0; tt < SEQT; tt += 4) {
    // ---- interval tt: bo=0, nbo=1024 ----
    GATE_STEP(0, 1024)
    if (w == 3) {
      XSTAGE(tt + 1, 1024, xQ1)
      if (tt > 0) FC_STEP(tt - 1, 0)
    }
    BAR()
    // ---- interval tt+1: bo=1024, nbo=0 ----
    GATE_STEP(1024, 0)
    if (w == 3) {
      XSTAGE(tt + 2, 0, xQ2)
      FC_STEP(tt, 1024)
    }
    BAR()
    // ---- interval tt+2: bo=0, nbo=1024 ----
    GATE_STEP(0, 1024)
    if (w == 3) {
      XSTAGE(tt + 3, 1024, xQ3)
      FC_STEP(tt + 1, 0)
    }
    BAR()
    // ---- interval tt+3: bo=1024, nbo=0 ----
    GATE_STEP(1024, 0)
    if (w == 3) {
      XSTAGE(tt + 4, 0, xQ0)
      FC_STEP(tt + 2, 1024)
    }
    BAR()
  }
  // epilogue: FC for the final step (h(255) lives in buf0)
  if (w == 3) FC_STEP(SEQT - 1, 0)

  // final hidden state from registers (2 real rows per lane)
  if (w < 3 && gvalid) {
#pragma unroll
    for (int i = 0; i < 2; ++i)
      hid[(size_t)(gb0 + lq * 2 + i) * H + u] = hold[i];
  }
}

extern "C" void kernel_launch(void* const* d_in, const int* in_sizes, int n_in,
                              void* d_out, int out_size, void* d_ws, size_t ws_size,
                              hipStream_t stream) {
  const float* x   = (const float*)d_in[0];
  const float* Wih = (const float*)d_in[1];
  const float* Whh = (const float*)d_in[2];
  const float* bih = (const float*)d_in[3];
  const float* bhh = (const float*)d_in[4];
  const float* Wfc = (const float*)d_in[5];
  const float* bfc = (const float*)d_in[6];
  float* out = (float*)d_out;
  float* hid = out + (size_t)BATCH * SEQT * NOUT;

  dim3 grid(BATCH / R);
  dim3 block(NT);
  hipLaunchKernelGGL(gru_mfma4, grid, block, 0, stream,
                     x, Wih, Whh, bih, bhh, Wfc, bfc, out, hid);
}